// Round 15
// baseline (67.760 us; speedup 1.0000x reference)
//
#include <hip/hip_runtime.h>
#include <hip/hip_bf16.h>
#include <math.h>

typedef __attribute__((ext_vector_type(8))) short short8;
typedef __attribute__((ext_vector_type(16))) float f32x16;

union U {
    unsigned u[4];
    short8 s;
};

struct FragH {         // one component (re or im) bf16 operand, 2 k-tiles
    U f[2];
};

static __device__ __forceinline__ unsigned short f2bf(float x) {
    __bf16 b = (__bf16)x;                       // RNE, native v_cvt on gfx950
    return __builtin_bit_cast(unsigned short, b);
}
static __device__ __forceinline__ unsigned packbf(float a, float b) {
    return (unsigned)f2bf(a) | ((unsigned)f2bf(b) << 16);
}

#define MFMA(A, B, C) __builtin_amdgcn_mfma_f32_32x32x16_bf16((A).s, (B).s, (C), 0, 0, 0)

// C/D accumulator -> bf16 A/B fragment via v_permlane32_swap_b32:
// swap(a,b): a.hi <-> b.lo => a = [a.lo;b.lo], b = [a.hi;b.hi]
static __device__ __forceinline__ void convertP(const f32x16& acc, FragH& out) {
    #pragma unroll
    for (int t = 0; t < 2; t++) {
        unsigned a0 = packbf(acc[8 * t + 0], acc[8 * t + 1]);
        unsigned a1 = packbf(acc[8 * t + 2], acc[8 * t + 3]);
        unsigned b0 = packbf(acc[8 * t + 4], acc[8 * t + 5]);
        unsigned b1 = packbf(acc[8 * t + 6], acc[8 * t + 7]);
        asm("v_permlane32_swap_b32 %0, %1" : "+v"(a0), "+v"(b0));
        asm("v_permlane32_swap_b32 %0, %1" : "+v"(a1), "+v"(b1));
        out.f[t].u[0] = a0;
        out.f[t].u[1] = a1;
        out.f[t].u[2] = b0;
        out.f[t].u[3] = b1;
    }
}

// R15: EVERYTHING fused into one kernel, zero workspace, zero extra dispatches.
//  - sT1 (twiddle, C/D order) computed per block via sincospif (8 KB LDS);
//  - F fragment tables computed per lane (16 sincospif, angles shared by the
//    3 components);
//  - filter spectrum kf[h] computed per WAVE by running k[h] through the SAME
//    stage1+twiddle+stage3 pipeline (real input: 12 MFMAs), written to sKF
//    (all 4 waves write identical values; benign), scaled by 1/1024;
//  - then 2 packed conv pairs per wave (R8-proven structure and reg profile).
// Grid 1024 blocks x 4 waves x 2 pairs = 8192 pairs; 8 blocks per h.
__global__ __launch_bounds__(256, 3) void conv_all(const float* __restrict__ u,
                                                   const float* __restrict__ kin,
                                                   float* __restrict__ out) {
    __shared__ float2 sT1[1024];    // 8 KB: twiddle exp(-2pi i rc/N), C/D order
    __shared__ float2 sKF[1024];    // 8 KB: FFT(k[h]) / 1024, C/D order

    const int tid = threadIdx.x;
    const int lane = tid & 63;
    const int wave = tid >> 6;
    const int col = lane & 31;
    const int hl = lane >> 5;
    const size_t tile_stride = (size_t)128 * 1024;

    const int p0 = blockIdx.x * 8 + wave * 2;   // this wave's pairs: p0, p0+1
    const int h = blockIdx.x >> 3;              // == p0>>6, uniform per block

    // ---- sT1: T1[m][l] = exp(-2pi i * (l&31)*row(m,l) / 1024)
    for (int i = tid; i < 1024; i += 256) {
        int m = i >> 6, l = i & 63;
        int row = (m & 3) + 8 * (m >> 2) + 4 * (l >> 5);
        int prod = (l & 31) * row;
        float st, ct;
        sincospif((float)prod / 512.0f, &st, &ct);
        sT1[i] = make_float2(ct, -st);
    }

    // ---- F fragment tables in regs: F[0]=cos, F[1]=-sin, F[2]=+sin.
    // Element (q of pair, vgpr v, ktile t): k = 16t+8hl+2v+q, j = col.
    U F[3][2];
    #pragma unroll
    for (int t = 0; t < 2; t++)
        #pragma unroll
        for (int v = 0; v < 4; v++) {
            float sa0, ca0, sa1, ca1;
            int k0 = 16 * t + 8 * hl + 2 * v;
            sincospif((float)((k0 * col) & 31) / 16.0f, &sa0, &ca0);
            sincospif((float)(((k0 + 1) * col) & 31) / 16.0f, &sa1, &ca1);
            F[0][t].u[v] = packbf(ca0, ca1);
            F[1][t].u[v] = packbf(-sa0, -sa1);
            F[2][t].u[v] = packbf(sa0, sa1);
        }
    __syncthreads();                            // sT1 ready

    const f32x16 Z16 = {0,0,0,0,0,0,0,0,0,0,0,0,0,0,0,0};

    // ---- kf-unit: run k[h] (real tile) through stage1+twiddle+stage3.
    {
        const float* kp = kin + ((size_t)h << 10);
        U Kr[2];
        #pragma unroll
        for (int t = 0; t < 2; t++)
            #pragma unroll
            for (int v = 0; v < 4; v++) {
                int r0 = (16 * t + 8 * hl + 2 * v) * 32 + col;
                Kr[t].u[v] = packbf(kp[r0], kp[r0 + 32]);
            }
        f32x16 aR = Z16, aI = Z16;
        #pragma unroll
        for (int t = 0; t < 2; t++) {
            aR = MFMA(Kr[t], F[0][t], aR);      // Yr = K@C
            aI = MFMA(Kr[t], F[1][t], aI);      // Yi = K@(-sin)
        }
        #pragma unroll
        for (int m = 0; m < 16; m++) {
            float2 tm = sT1[m * 64 + lane];
            float rr = aR[m] * tm.x - aI[m] * tm.y;
            float ii = aR[m] * tm.y + aI[m] * tm.x;
            aR[m] = rr; aI[m] = ii;
        }
        FragH Yr, Yi;
        convertP(aR, Yr);
        convertP(aI, Yi);
        f32x16 bR = Z16, bI = Z16;
        #pragma unroll
        for (int t = 0; t < 2; t++) {
            bR = MFMA(F[0][t], Yr.f[t], bR); bR = MFMA(F[2][t], Yi.f[t], bR);
            bI = MFMA(F[0][t], Yi.f[t], bI); bI = MFMA(F[1][t], Yr.f[t], bI);
        }
        // All 4 waves write identical values (same h): benign.
        #pragma unroll
        for (int m = 0; m < 16; m++)
            sKF[m * 64 + lane] = make_float2(bR[m] * (1.0f / 1024.0f),
                                             bI[m] * (1.0f / 1024.0f));
    }
    __syncthreads();                            // sKF ready

    // ---- Two packed conv pairs (R8 structure).
    for (int j = 0; j < 2; j++) {
        const int b0 = ((p0 + j) & 63) * 2;
        const float* upr = u + ((size_t)(b0 * 128 + h) << 10);
        const float* upi = upr + tile_stride;

        U Xr[2], Xi[2];
        #pragma unroll
        for (int t = 0; t < 2; t++)
            #pragma unroll
            for (int v = 0; v < 4; v++) {
                int r0 = (16 * t + 8 * hl + 2 * v) * 32 + col;
                Xr[t].u[v] = packbf(upr[r0], upr[r0 + 32]);
                Xi[t].u[v] = packbf(upi[r0], upi[r0 + 32]);
            }

        // Stage 1: Y^T = Z^T @ F   (Yr = Xr@C + Xi@sin ; Yi = Xr@S + Xi@C)
        f32x16 aR = Z16, aI = Z16;
        #pragma unroll
        for (int t = 0; t < 2; t++) {
            aR = MFMA(Xr[t], F[0][t], aR); aR = MFMA(Xi[t], F[2][t], aR);
            aI = MFMA(Xr[t], F[1][t], aI); aI = MFMA(Xi[t], F[0][t], aI);
        }
        #pragma unroll
        for (int m = 0; m < 16; m++) {                 // twiddle (1/N in kf)
            float2 tm = sT1[m * 64 + lane];
            float rr = aR[m] * tm.x - aI[m] * tm.y;
            float ii = aR[m] * tm.y + aI[m] * tm.x;
            aR[m] = rr; aI[m] = ii;
        }
        FragH Yr, Yi;
        convertP(aR, Yr);
        convertP(aI, Yi);

        // Stage 3: Z^T = F @ Y^T  (Zr = C@Yr + sin@Yi ; Zi = C@Yi + S@Yr)
        f32x16 bR = Z16, bI = Z16;
        #pragma unroll
        for (int t = 0; t < 2; t++) {
            bR = MFMA(F[0][t], Yr.f[t], bR); bR = MFMA(F[2][t], Yi.f[t], bR);
            bI = MFMA(F[0][t], Yi.f[t], bI); bI = MFMA(F[1][t], Yr.f[t], bI);
        }
        #pragma unroll
        for (int m = 0; m < 16; m++) {                 // filter (has 1/N)
            float2 kv = sKF[m * 64 + lane];
            float rr = bR[m] * kv.x - bI[m] * kv.y;
            float ii = bR[m] * kv.y + bI[m] * kv.x;
            bR[m] = rr; bI[m] = ii;
        }
        FragH Zr, Zi;
        convertP(bR, Zr);
        convertP(bI, Zi);

        // Stage 5: W = Z @ Finv  (Wr = Zr@C + Zi@S ; Wi = Zr@sin + Zi@C)
        aR = Z16; aI = Z16;
        #pragma unroll
        for (int t = 0; t < 2; t++) {
            aR = MFMA(Zr.f[t], F[0][t], aR); aR = MFMA(Zi.f[t], F[1][t], aR);
            aI = MFMA(Zr.f[t], F[2][t], aI); aI = MFMA(Zi.f[t], F[0][t], aI);
        }
        #pragma unroll
        for (int m = 0; m < 16; m++) {                 // conj twiddle (no scale)
            float2 tm = sT1[m * 64 + lane];
            float rr = aR[m] * tm.x + aI[m] * tm.y;
            float ii = aI[m] * tm.x - aR[m] * tm.y;
            aR[m] = rr; aI[m] = ii;
        }
        FragH Wr, Wi;
        convertP(aR, Wr);
        convertP(aI, Wi);

        // Stage 7: y = Finv @ W  (yR = C@Wr + S@Wi ; yI = C@Wi + sin@Wr)
        f32x16 yR = Z16, yI = Z16;
        #pragma unroll
        for (int t = 0; t < 2; t++) {
            yR = MFMA(F[0][t], Wr.f[t], yR); yR = MFMA(F[1][t], Wi.f[t], yR);
            yI = MFMA(F[0][t], Wi.f[t], yI); yI = MFMA(F[2][t], Wr.f[t], yI);
        }
        float* opr = out + ((size_t)(b0 * 128 + h) << 10);
        float* opi = opr + tile_stride;
        #pragma unroll
        for (int m = 0; m < 16; m++) {
            int off = ((m & 3) + 8 * (m >> 2) + 4 * hl) * 32 + col;
            opr[off] = yR[m];
            opi[off] = yI[m];
        }
    }
}

extern "C" void kernel_launch(void* const* d_in, const int* in_sizes, int n_in,
                              void* d_out, int out_size, void* d_ws, size_t ws_size,
                              hipStream_t stream) {
    const float* u = (const float*)d_in[0];   // (B=128, H=128, N=1024)
    const float* k = (const float*)d_in[1];   // (H=128, N=1024)
    float* out = (float*)d_out;               // (B, H, N) float32

    conv_all<<<1024, 256, 0, stream>>>(u, k, out);
}